// Round 6
// baseline (792.282 us; speedup 1.0000x reference)
//
#include <hip/hip_runtime.h>
#include <stdint.h>

typedef __attribute__((ext_vector_type(8))) short bhalf8;
typedef __attribute__((ext_vector_type(4))) float fx4;

__device__ __forceinline__ unsigned short f2bf(float f) {
    unsigned u = __builtin_bit_cast(unsigned, f);
    unsigned r = (u + 0x7fffu + ((u >> 16) & 1u)) >> 16;
    return (unsigned short)r;
}
__device__ __forceinline__ float bf2f(unsigned short h) {
    unsigned u = ((unsigned)h) << 16;
    return __builtin_bit_cast(float, u);
}
__device__ __forceinline__ float lrelu(float v) { return v > 0.f ? v : 0.2f * v; }

typedef __attribute__((address_space(1))) void as1_void;
typedef __attribute__((address_space(3))) void as3_void;
__device__ __forceinline__ void gl_lds16(const void* g, void* l) {
    __builtin_amdgcn_global_load_lds((as1_void*)(void*)g, (as3_void*)l, 16, 0, 0);
}

// ---------------- styles: s = w @ a^T + b  (one wave per output) ----------------
__global__ __launch_bounds__(256) void style_kernel(
    const float* __restrict__ w,
    const float* __restrict__ a1w, const float* __restrict__ a1b,
    const float* __restrict__ a2w, const float* __restrict__ a2b,
    const float* __restrict__ a3w, const float* __restrict__ a3b,
    float* __restrict__ s1, float* __restrict__ s2, float* __restrict__ s3)
{
    int gw = blockIdx.x * 4 + (threadIdx.x >> 6);   // 0..4095
    int lane = threadIdx.x & 63;
    int b = gw >> 10, r = gw & 1023;
    const float* arow; const float* abias; float* dst;
    if (r < 512)      { arow = a1w + (size_t)r * 512;        abias = a1b + r;       dst = s1 + b * 512 + r; }
    else if (r < 768) { int rr = r - 512; arow = a2w + (size_t)rr * 512; abias = a2b + rr; dst = s2 + b * 256 + rr; }
    else              { int rr = r - 768; arow = a3w + (size_t)rr * 512; abias = a3b + rr; dst = s3 + b * 256 + rr; }
    const float* wrow = w + b * 512;
    float acc = 0.f;
    #pragma unroll
    for (int j = 0; j < 8; ++j) {
        int c = lane + j * 64;
        acc += wrow[c] * arow[c];
    }
    #pragma unroll
    for (int off = 32; off; off >>= 1) acc += __shfl_down(acc, off, 64);
    if (lane == 0) *dst = acc + *abias;
}

// ---------------- demod: d[b,o] = rsqrt(sum_{i,tap}(w*s)^2 + eps) ----------------
__global__ __launch_bounds__(256) void demod_kernel(
    const float* __restrict__ w1, const float* __restrict__ w2,
    const float* __restrict__ s1, const float* __restrict__ s2,
    float* __restrict__ d1, float* __restrict__ d2)
{
    int blk = blockIdx.x;                 // 2048 blocks
    int conv = blk >> 10, b = (blk >> 8) & 3, o = blk & 255;
    int t = threadIdx.x;
    int cin = conv ? 256 : 512;
    const float* s = conv ? (s2 + b * 256) : (s1 + b * 512);
    const float* row = (conv ? w2 : w1) + (size_t)o * cin * 9;
    __shared__ float sv[512];
    for (int i = t; i < cin; i += 256) { float v = s[i]; sv[i] = v * v; }
    __syncthreads();
    float sum = 0.f;
    int n = cin * 9;
    for (int k = t; k < n; k += 256) {
        float v = row[k];
        sum += v * v * sv[k / 9];
    }
    #pragma unroll
    for (int off = 32; off; off >>= 1) sum += __shfl_down(sum, off, 64);
    __shared__ float red[4];
    if ((t & 63) == 0) red[t >> 6] = sum;
    __syncthreads();
    if (t == 0) {
        float tot = red[0] + red[1] + red[2] + red[3];
        (conv ? d2 : d1)[b * 256 + o] = rsqrtf(tot + 1e-8f);
    }
}

// ---------------- pack weights to bf16, fragment-linear layout ----------------
// layout: [mblk][dy][ic][dx][kh][m(128)][e(8)]
__global__ __launch_bounds__(256) void pack_kernel(
    const float* __restrict__ w1, const float* __restrict__ w2,
    unsigned short* __restrict__ wp1, unsigned short* __restrict__ wp2)
{
    int tid = blockIdx.x * 256 + threadIdx.x;
    const int N1 = 1179648, N2 = 589824;
    if (tid < N1) {
        int e = tid & 7, m = (tid >> 3) & 127, kh = (tid >> 10) & 3;
        int dx = (tid >> 12) % 3, ic = (tid / 12288) & 15;
        int dy = (tid / 196608) % 3, mblk = tid / 589824;
        int o = mblk * 128 + m, ci = ic * 32 + kh * 8 + e;
        wp1[tid] = f2bf(w1[((size_t)o * 512 + ci) * 9 + dy * 3 + dx]);
    } else if (tid < N1 + N2) {
        int t2 = tid - N1;
        int e = t2 & 7, m = (t2 >> 3) & 127, kh = (t2 >> 10) & 3;
        int dx = (t2 >> 12) % 3, ic = (t2 / 12288) & 7;
        int dy = (t2 / 98304) % 3, mblk = t2 / 294912;
        int o = mblk * 128 + m, ci = ic * 32 + kh * 8 + e;
        wp2[t2] = f2bf(w2[((size_t)o * 256 + ci) * 9 + dy * 3 + dx]);
    }
}

// ---------------- bilinear 2x upsample + s1 modulate -> bf16 channels-last ----------------
__global__ __launch_bounds__(256) void upsample_kernel(
    const float* __restrict__ x, const float* __restrict__ s1,
    unsigned short* __restrict__ xu)   // [4][128][128][512]
{
    __shared__ float Lt[3][64][68];   // 52224 B -> 3 blocks/CU
    const int bid = blockIdx.x;       // grid 2048 = b(4) x k(64) x cchunk(8)
    const int cch = bid & 7, k = (bid >> 3) & 63, b = bid >> 9;
    const int c0 = cch * 64;
    const int t = threadIdx.x;

    {
        const int px4 = t & 15, cc4 = t >> 4;   // cc4 0..15
        #pragma unroll
        for (int r = 0; r < 3; ++r) {
            int sy = k - 1 + r; sy = sy < 0 ? 0 : (sy > 63 ? 63 : sy);
            float4 v[4];
            #pragma unroll
            for (int j = 0; j < 4; ++j)
                v[j] = *(const float4*)&x[((size_t)(b * 512 + c0 + cc4 * 4 + j) * 64 + sy) * 64 + px4 * 4];
            #pragma unroll
            for (int o = 0; o < 4; ++o) {
                fx4 w4;
                w4[0] = ((const float*)&v[0])[o];
                w4[1] = ((const float*)&v[1])[o];
                w4[2] = ((const float*)&v[2])[o];
                w4[3] = ((const float*)&v[3])[o];
                *(fx4*)&Lt[r][px4 * 4 + o][cc4 * 4] = w4;
            }
        }
    }
    __syncthreads();

    const int oct = t & 7, xob = t >> 3;   // xob 0..31
    float sty[8];
    #pragma unroll
    for (int j = 0; j < 8; ++j) sty[j] = s1[b * 512 + c0 + oct * 8 + j];

    #pragma unroll
    for (int half = 0; half < 2; ++half) {     // out row 2k+half
        const int yo = 2 * k + half;
        const int rA = half ? 1 : 0, rB = rA + 1;
        const float wyA = half ? 0.75f : 0.25f, wyB = half ? 0.25f : 0.75f;
        #pragma unroll
        for (int i = 0; i < 4; ++i) {
            const int xo = xob + i * 32;
            const int kk = xo >> 1;
            int sx0, sx1; float wx0, wx1;
            if ((xo & 1) == 0) { sx0 = kk > 0 ? kk - 1 : 0; sx1 = kk; wx0 = 0.25f; wx1 = 0.75f; }
            else               { sx0 = kk; sx1 = kk < 63 ? kk + 1 : 63; wx0 = 0.75f; wx1 = 0.25f; }
            unsigned pk[4];
            #pragma unroll
            for (int h = 0; h < 2; ++h) {
                const fx4 a0 = *(const fx4*)&Lt[rA][sx0][oct * 8 + h * 4];
                const fx4 a1 = *(const fx4*)&Lt[rA][sx1][oct * 8 + h * 4];
                const fx4 b0 = *(const fx4*)&Lt[rB][sx0][oct * 8 + h * 4];
                const fx4 b1 = *(const fx4*)&Lt[rB][sx1][oct * 8 + h * 4];
                #pragma unroll
                for (int j2 = 0; j2 < 2; ++j2) {
                    float v0 = wyA * (wx0 * a0[j2 * 2]     + wx1 * a1[j2 * 2])
                             + wyB * (wx0 * b0[j2 * 2]     + wx1 * b1[j2 * 2]);
                    float v1 = wyA * (wx0 * a0[j2 * 2 + 1] + wx1 * a1[j2 * 2 + 1])
                             + wyB * (wx0 * b0[j2 * 2 + 1] + wx1 * b1[j2 * 2 + 1]);
                    v0 *= sty[h * 4 + j2 * 2];
                    v1 *= sty[h * 4 + j2 * 2 + 1];
                    pk[h * 2 + j2] = (unsigned)f2bf(v0) | ((unsigned)f2bf(v1) << 16);
                }
            }
            *(int4*)&xu[((size_t)(b * 128 + yo) * 128 + xo) * 512 + c0 + oct * 8] =
                make_int4(pk[0], pk[1], pk[2], pk[3]);
        }
    }
}

// ---------------- 3x3 conv, implicit im2col, bf16 MFMA 16x16x32 ----------------
// Fine-phase counted-vmcnt schedule (T3+T4) at 2 blocks/CU (72KB LDS):
//   phase p=(ic,dy,dx): { s_waitcnt vmcnt(N); s_barrier; issue loads; 8 ds_read; 16 MFMA }
// A: 8KB chunk per phase, 3-slot ring, slot==dx (p%3==dx), prefetch distance 2 phases.
// B: 8KB row per load, 6-slot ring slot(ic,r)=(4ic+r)%6; issued at dx==0 phases
//    (dy0: rows0,1 of ic+1; dy1: row2; dy2: row3), each >=3 phases before use.
// vmcnt(N) accounting (issues-after-A(p), issue order: A first then B within a phase;
// e0=(y0==0), e1=(y0==126) drop one B load, block-uniform):
//   steady (ic<NIC-1): dx0 -> 1; dy0,dx>0 -> 3-e0; dy1,dx>0 -> 2; dy2,dx>0 -> 2-e1
//   tail (ic==NIC-1): 1 everywhere, final phase 0.   first phase overall: 2-e1.
template<int CIN, bool IS_CONV2>
__global__ __launch_bounds__(512, 4) void conv3x3_kernel(
    const unsigned short* __restrict__ inp,
    const unsigned short* __restrict__ wpack,
    const float* __restrict__ dvec,
    const float* __restrict__ bias,
    const float* __restrict__ post,
    unsigned short* __restrict__ outmod,
    float* __restrict__ outf)
{
    constexpr int NIC = CIN / 32;
    __shared__ __attribute__((aligned(16))) short Alds[3][4096];     // 24576 B
    __shared__ __attribute__((aligned(16))) short Blds[6][128][32];  // 49152 B
    const int tid = threadIdx.x;
    const int lane = tid & 63;
    const int wvi = tid >> 6;         // 0..7
    const int bid = blockIdx.x;       // grid 512 = b(4) x mblk(2) x y2(64)
    const int y0 = (bid & 63) << 1;
    const int mblk = (bid >> 6) & 1;
    const int b = bid >> 7;
    const int wm = (wvi >> 2) * 64;
    const int row = (wvi >> 1) & 1;   // which of the 2 output rows
    const int wn = (wvi & 1) * 64;
    const int lhi = lane >> 4;
    const int llo = lane & 15;
    const int e0 = (y0 == 0) ? 1 : 0;
    const int e1 = (y0 == 126) ? 1 : 0;

    const int xg = tid >> 2, i8 = tid & 3;
    const int i8s = i8 ^ ((xg >> 1) & 3);

#define WAITVM(N) asm volatile("s_waitcnt vmcnt(" #N ") lgkmcnt(0)" ::: "memory")
#define CBAR()    asm volatile("" ::: "memory")

    // one 8KB A chunk (ic,dy,dx) -> Alds[slot]; 1 gl_lds16/thread
    auto stageA1 = [&](int qic, int qdy, int qdx, int slot) {
        const unsigned short* asrc = wpack + ((size_t)(mblk * 3 + qdy) * NIC + qic) * 12288
                                           + qdx * 4096;
        gl_lds16(asrc + (size_t)tid * 8, (char*)&Alds[slot][0] + tid * 16);
    };
    // one 8KB B row (icn, rr) -> Blds[slot]; 1 gl_lds16/thread (ds-write zeros if halo)
    auto stageB1 = [&](int icn, int rr, int slot) {
        const int yy = y0 - 1 + rr;
        char* dstB = (char*)&Blds[slot][0][0] + tid * 16;
        if ((unsigned)yy < 128u) {
            gl_lds16(inp + ((size_t)(b * 128 + yy) * 128 + xg) * CIN + icn * 32 + i8s * 8, dstB);
        } else {
            *(int4*)dstB = make_int4(0, 0, 0, 0);
        }
    };

    fx4 acc[4][4];
    #pragma unroll
    for (int mt = 0; mt < 4; ++mt)
        #pragma unroll
        for (int nt = 0; nt < 4; ++nt) acc[mt][nt] = (fx4){0.f, 0.f, 0.f, 0.f};

    // prologue issue order (accounting depends on it): A(0), A(1), B rows 0..3 of ic=0
    stageA1(0, 0, 0, 0); CBAR();
    stageA1(0, 0, 1, 1); CBAR();
    stageB1(0, 0, 0); CBAR();
    stageB1(0, 1, 1); CBAR();
    stageB1(0, 2, 2); CBAR();
    stageB1(0, 3, 3); CBAR();

    int bbase = 0;   // slot(ic, r) = (bbase + r) mod 6, bbase = (4*ic) mod 6
    for (int ic = 0; ic < NIC; ++ic) {
        const bool lastic = (ic == NIC - 1);
        #pragma unroll
        for (int dy = 0; dy < 3; ++dy) {
            #pragma unroll
            for (int dx = 0; dx < 3; ++dx) {
                // ---- counted wait + barrier ----
                int n;
                if (ic == 0 && dy == 0 && dx == 0) n = 2 - e1;
                else if (lastic) n = (dy == 2 && dx == 2) ? 0 : 1;
                else if (dx == 0) n = 1;
                else if (dy == 0) n = 3 - e0;
                else if (dy == 1) n = 2;
                else n = 2 - e1;
                if (n == 0) WAITVM(0);
                else if (n == 1) WAITVM(1);
                else if (n == 2) WAITVM(2);
                else WAITVM(3);
                __builtin_amdgcn_s_barrier();
                __builtin_amdgcn_sched_barrier(0);
                // ---- issue: A(p+2) then B rows (order matters for vmcnt) ----
                {
                    const int poff = 3 * dy + dx + 2;
                    if (!(lastic && dy == 2 && dx >= 1)) {
                        const int qic = ic + (poff >= 9 ? 1 : 0);
                        const int qoff = poff >= 9 ? poff - 9 : poff;
                        stageA1(qic, qoff / 3, qoff % 3, (dx + 2) % 3);
                        CBAR();
                    }
                }
                if (dx == 0 && !lastic) {
                    if (dy == 0) {
                        int s4 = bbase + 4; if (s4 >= 6) s4 -= 6;
                        int s5 = bbase + 5; if (s5 >= 6) s5 -= 6;
                        stageB1(ic + 1, 0, s4); CBAR();
                        stageB1(ic + 1, 1, s5); CBAR();
                    } else if (dy == 1) {
                        stageB1(ic + 1, 2, bbase); CBAR();
                    } else {
                        int s1b = bbase + 1; if (s1b >= 6) s1b -= 6;
                        stageB1(ic + 1, 3, s1b); CBAR();
                    }
                }
                // ---- compute: 4 A-frag + 4 B-frag ds_read_b128, 16 MFMA ----
                int sb = bbase + row + dy; if (sb >= 6) sb -= 6;
                const short* Brow = &Blds[sb][0][0];
                bhalf8 af[4], bfr[4];
                #pragma unroll
                for (int mt = 0; mt < 4; ++mt)
                    af[mt] = *(const bhalf8*)&Alds[dx][(lhi * 128 + wm + mt * 16 + llo) * 8];
                #pragma unroll
                for (int nt = 0; nt < 4; ++nt) {
                    const int s = wn + nt * 16 + llo + dx;
                    if ((nt == 0 && dx == 0) || (nt == 3 && dx == 2)) {
                        const bool edge = (s == 0) || (s == 129);
                        const int sp = edge ? 0 : (s - 1);
                        const int key = (sp >> 1) & 3;
                        bhalf8 v = *(const bhalf8*)&Brow[sp * 32 + ((lhi ^ key) << 3)];
                        bhalf8 z = {0, 0, 0, 0, 0, 0, 0, 0};
                        bfr[nt] = edge ? z : v;
                    } else {
                        const int sp = s - 1;
                        const int key = (sp >> 1) & 3;
                        bfr[nt] = *(const bhalf8*)&Brow[sp * 32 + ((lhi ^ key) << 3)];
                    }
                }
                __builtin_amdgcn_s_setprio(1);
                #pragma unroll
                for (int mt = 0; mt < 4; ++mt)
                    #pragma unroll
                    for (int nt = 0; nt < 4; ++nt)
                        acc[mt][nt] = __builtin_amdgcn_mfma_f32_16x16x32_bf16(
                            af[mt], bfr[nt], acc[mt][nt], 0, 0, 0);
                __builtin_amdgcn_s_setprio(0);
            }
        }
        bbase += 4; if (bbase >= 6) bbase -= 6;
    }
#undef WAITVM
#undef CBAR

    // epilogue
    const int y = y0 + row;
    #pragma unroll
    for (int mt = 0; mt < 4; ++mt) {
        const int o0 = mblk * 128 + wm + mt * 16 + lhi * 4;
        const fx4 d4 = *(const fx4*)(dvec + b * 256 + o0);
        const fx4 bb4 = *(const fx4*)(bias + o0);
        const fx4 p4 = *(const fx4*)(post + b * 256 + o0);
        #pragma unroll
        for (int nt = 0; nt < 4; ++nt) {
            const int xo = wn + nt * 16 + llo;
            unsigned lo = 0, hi = 0;
            #pragma unroll
            for (int r = 0; r < 4; ++r) {
                float v = acc[mt][nt][r] * d4[r] + bb4[r];
                v = lrelu(v);
                if (IS_CONV2)
                    outf[(((size_t)b * 256 + o0 + r) * 128 + y) * 128 + xo] = v;
                unsigned short ub = f2bf(v * p4[r]);
                if (r < 2) lo |= (unsigned)ub << (16 * r);
                else       hi |= (unsigned)ub << (16 * (r - 2));
            }
            *(uint2*)&outmod[((size_t)(b * 128 + y) * 128 + xo) * 256 + o0] = make_uint2(lo, hi);
        }
    }
}

// ---------------- 1x1 to_rgb on h*s3 (bf16), coalesced: 4 lanes per pixel ----------------
__global__ __launch_bounds__(256) void rgb_kernel(
    const unsigned short* __restrict__ hs3,
    const float* __restrict__ w3, const float* __restrict__ b3,
    float* __restrict__ out)   // [4][3][128][128]
{
    __shared__ float wl[768];
    int t = threadIdx.x;
    for (int i = t; i < 768; i += 256) wl[i] = w3[i];
    __syncthreads();
    int p = blockIdx.x * 64 + (t >> 2);   // global pixel 0..65535  (grid = 1024)
    int q = t & 3;                        // channel-quarter
    const unsigned short* src = hs3 + (size_t)p * 256 + q * 64;
    float a0 = 0.f, a1 = 0.f, a2 = 0.f;
    #pragma unroll
    for (int c8 = 0; c8 < 64; c8 += 8) {
        int4 pk = *(const int4*)(src + c8);
        #pragma unroll
        for (int qq = 0; qq < 4; ++qq) {
            unsigned uu = ((const unsigned*)&pk)[qq];
            float ve = bf2f((unsigned short)(uu & 0xffffu));
            float vo = bf2f((unsigned short)(uu >> 16));
            int c = q * 64 + c8 + qq * 2;
            a0 += ve * wl[c] + vo * wl[c + 1];
            a1 += ve * wl[256 + c] + vo * wl[256 + c + 1];
            a2 += ve * wl[512 + c] + vo * wl[512 + c + 1];
        }
    }
    a0 += __shfl_xor(a0, 1, 64); a0 += __shfl_xor(a0, 2, 64);
    a1 += __shfl_xor(a1, 1, 64); a1 += __shfl_xor(a1, 2, 64);
    a2 += __shfl_xor(a2, 1, 64); a2 += __shfl_xor(a2, 2, 64);
    int b = p >> 14, yx = p & 16383;
    if (q < 3) {
        float v = (q == 0) ? a0 : (q == 1) ? a1 : a2;
        out[((size_t)b * 3 + q) * 16384 + yx] = lrelu(v + b3[q]);
    }
}

extern "C" void kernel_launch(void* const* d_in, const int* in_sizes, int n_in,
                              void* d_out, int out_size, void* d_ws, size_t ws_size,
                              hipStream_t stream) {
    const float* x   = (const float*)d_in[0];
    const float* w   = (const float*)d_in[1];
    const float* w1  = (const float*)d_in[2];
    const float* b1  = (const float*)d_in[3];
    const float* a1w = (const float*)d_in[4];
    const float* a1b = (const float*)d_in[5];
    const float* w2  = (const float*)d_in[6];
    const float* b2  = (const float*)d_in[7];
    const float* a2w = (const float*)d_in[8];
    const float* a2b = (const float*)d_in[9];
    const float* w3  = (const float*)d_in[10];
    const float* b3  = (const float*)d_in[11];
    const float* a3w = (const float*)d_in[12];
    const float* a3b = (const float*)d_in[13];

    char* ws = (char*)d_ws;
    unsigned short* xu  = (unsigned short*)(ws);                 // 67108864 B [4][128][128][512] bf16
    unsigned short* hs3 = (unsigned short*)(ws);                 // aliases xu (xu dead after conv1)
    unsigned short* t1  = (unsigned short*)(ws + 67108864);      // 33554432 B [4][128][128][256] bf16
    unsigned short* wp1 = (unsigned short*)(ws + 100663296);     // 2359296 B
    unsigned short* wp2 = (unsigned short*)(ws + 103022592);     // 1179648 B
    float* s1 = (float*)(ws + 104202240);                        // 4*512
    float* s2 = (float*)(ws + 104210432);                        // 4*256
    float* s3 = (float*)(ws + 104214528);                        // 4*256
    float* d1 = (float*)(ws + 104218624);                        // 4*256
    float* d2 = (float*)(ws + 104222720);                        // 4*256

    float* h_out   = (float*)d_out;
    float* rgb_out = h_out + 16777216;

    style_kernel<<<1024, 256, 0, stream>>>(w, a1w, a1b, a2w, a2b, a3w, a3b, s1, s2, s3);
    demod_kernel<<<2048, 256, 0, stream>>>(w1, w2, s1, s2, d1, d2);
    pack_kernel<<<6912, 256, 0, stream>>>(w1, w2, wp1, wp2);
    upsample_kernel<<<2048, 256, 0, stream>>>(x, s1, xu);
    conv3x3_kernel<512, false><<<512, 512, 0, stream>>>(xu, wp1, d1, b1, s2, t1, nullptr);
    conv3x3_kernel<256, true><<<512, 512, 0, stream>>>(t1, wp2, d2, b2, s3, hs3, h_out);
    rgb_kernel<<<1024, 256, 0, stream>>>(hs3, w3, b3, rgb_out);
}

// Round 7
// 354.711 us; speedup vs baseline: 2.2336x; 2.2336x over previous
//
#include <hip/hip_runtime.h>
#include <stdint.h>

typedef __attribute__((ext_vector_type(8))) short bhalf8;
typedef __attribute__((ext_vector_type(4))) float fx4;

__device__ __forceinline__ unsigned short f2bf(float f) {
    unsigned u = __builtin_bit_cast(unsigned, f);
    unsigned r = (u + 0x7fffu + ((u >> 16) & 1u)) >> 16;
    return (unsigned short)r;
}
__device__ __forceinline__ float bf2f(unsigned short h) {
    unsigned u = ((unsigned)h) << 16;
    return __builtin_bit_cast(float, u);
}
__device__ __forceinline__ float lrelu(float v) { return v > 0.f ? v : 0.2f * v; }

typedef __attribute__((address_space(1))) void as1_void;
typedef __attribute__((address_space(3))) void as3_void;
__device__ __forceinline__ void gl_lds16(const void* g, void* l) {
    __builtin_amdgcn_global_load_lds((as1_void*)(void*)g, (as3_void*)l, 16, 0, 0);
}

// ---------------- styles: s = w @ a^T + b  (one wave per output) ----------------
__global__ __launch_bounds__(256) void style_kernel(
    const float* __restrict__ w,
    const float* __restrict__ a1w, const float* __restrict__ a1b,
    const float* __restrict__ a2w, const float* __restrict__ a2b,
    const float* __restrict__ a3w, const float* __restrict__ a3b,
    float* __restrict__ s1, float* __restrict__ s2, float* __restrict__ s3)
{
    int gw = blockIdx.x * 4 + (threadIdx.x >> 6);   // 0..4095
    int lane = threadIdx.x & 63;
    int b = gw >> 10, r = gw & 1023;
    const float* arow; const float* abias; float* dst;
    if (r < 512)      { arow = a1w + (size_t)r * 512;        abias = a1b + r;       dst = s1 + b * 512 + r; }
    else if (r < 768) { int rr = r - 512; arow = a2w + (size_t)rr * 512; abias = a2b + rr; dst = s2 + b * 256 + rr; }
    else              { int rr = r - 768; arow = a3w + (size_t)rr * 512; abias = a3b + rr; dst = s3 + b * 256 + rr; }
    const float* wrow = w + b * 512;
    float acc = 0.f;
    #pragma unroll
    for (int j = 0; j < 8; ++j) {
        int c = lane + j * 64;
        acc += wrow[c] * arow[c];
    }
    #pragma unroll
    for (int off = 32; off; off >>= 1) acc += __shfl_down(acc, off, 64);
    if (lane == 0) *dst = acc + *abias;
}

// ---------------- demod: d[b,o] = rsqrt(sum_{i,tap}(w*s)^2 + eps) ----------------
__global__ __launch_bounds__(256) void demod_kernel(
    const float* __restrict__ w1, const float* __restrict__ w2,
    const float* __restrict__ s1, const float* __restrict__ s2,
    float* __restrict__ d1, float* __restrict__ d2)
{
    int blk = blockIdx.x;                 // 2048 blocks
    int conv = blk >> 10, b = (blk >> 8) & 3, o = blk & 255;
    int t = threadIdx.x;
    int cin = conv ? 256 : 512;
    const float* s = conv ? (s2 + b * 256) : (s1 + b * 512);
    const float* row = (conv ? w2 : w1) + (size_t)o * cin * 9;
    __shared__ float sv[512];
    for (int i = t; i < cin; i += 256) { float v = s[i]; sv[i] = v * v; }
    __syncthreads();
    float sum = 0.f;
    int n = cin * 9;
    for (int k = t; k < n; k += 256) {
        float v = row[k];
        sum += v * v * sv[k / 9];
    }
    #pragma unroll
    for (int off = 32; off; off >>= 1) sum += __shfl_down(sum, off, 64);
    __shared__ float red[4];
    if ((t & 63) == 0) red[t >> 6] = sum;
    __syncthreads();
    if (t == 0) {
        float tot = red[0] + red[1] + red[2] + red[3];
        (conv ? d2 : d1)[b * 256 + o] = rsqrtf(tot + 1e-8f);
    }
}

// ---------------- pack weights to bf16, fragment-linear layout ----------------
// layout: [mblk][dy][ic][dx][kh][m(128)][e(8)]
__global__ __launch_bounds__(256) void pack_kernel(
    const float* __restrict__ w1, const float* __restrict__ w2,
    unsigned short* __restrict__ wp1, unsigned short* __restrict__ wp2)
{
    int tid = blockIdx.x * 256 + threadIdx.x;
    const int N1 = 1179648, N2 = 589824;
    if (tid < N1) {
        int e = tid & 7, m = (tid >> 3) & 127, kh = (tid >> 10) & 3;
        int dx = (tid >> 12) % 3, ic = (tid / 12288) & 15;
        int dy = (tid / 196608) % 3, mblk = tid / 589824;
        int o = mblk * 128 + m, ci = ic * 32 + kh * 8 + e;
        wp1[tid] = f2bf(w1[((size_t)o * 512 + ci) * 9 + dy * 3 + dx]);
    } else if (tid < N1 + N2) {
        int t2 = tid - N1;
        int e = t2 & 7, m = (t2 >> 3) & 127, kh = (t2 >> 10) & 3;
        int dx = (t2 >> 12) % 3, ic = (t2 / 12288) & 7;
        int dy = (t2 / 98304) % 3, mblk = t2 / 294912;
        int o = mblk * 128 + m, ci = ic * 32 + kh * 8 + e;
        wp2[t2] = f2bf(w2[((size_t)o * 256 + ci) * 9 + dy * 3 + dx]);
    }
}

// ---------------- bilinear 2x upsample + s1 modulate -> bf16 channels-last ----------------
__global__ __launch_bounds__(256) void upsample_kernel(
    const float* __restrict__ x, const float* __restrict__ s1,
    unsigned short* __restrict__ xu)   // [4][128][128][512]
{
    __shared__ float Lt[3][64][68];   // 52224 B -> 3 blocks/CU
    const int bid = blockIdx.x;       // grid 2048 = b(4) x k(64) x cchunk(8)
    const int cch = bid & 7, k = (bid >> 3) & 63, b = bid >> 9;
    const int c0 = cch * 64;
    const int t = threadIdx.x;

    {
        const int px4 = t & 15, cc4 = t >> 4;   // cc4 0..15
        #pragma unroll
        for (int r = 0; r < 3; ++r) {
            int sy = k - 1 + r; sy = sy < 0 ? 0 : (sy > 63 ? 63 : sy);
            float4 v[4];
            #pragma unroll
            for (int j = 0; j < 4; ++j)
                v[j] = *(const float4*)&x[((size_t)(b * 512 + c0 + cc4 * 4 + j) * 64 + sy) * 64 + px4 * 4];
            #pragma unroll
            for (int o = 0; o < 4; ++o) {
                fx4 w4;
                w4[0] = ((const float*)&v[0])[o];
                w4[1] = ((const float*)&v[1])[o];
                w4[2] = ((const float*)&v[2])[o];
                w4[3] = ((const float*)&v[3])[o];
                *(fx4*)&Lt[r][px4 * 4 + o][cc4 * 4] = w4;
            }
        }
    }
    __syncthreads();

    const int oct = t & 7, xob = t >> 3;   // xob 0..31
    float sty[8];
    #pragma unroll
    for (int j = 0; j < 8; ++j) sty[j] = s1[b * 512 + c0 + oct * 8 + j];

    #pragma unroll
    for (int half = 0; half < 2; ++half) {     // out row 2k+half
        const int yo = 2 * k + half;
        const int rA = half ? 1 : 0, rB = rA + 1;
        const float wyA = half ? 0.75f : 0.25f, wyB = half ? 0.25f : 0.75f;
        #pragma unroll
        for (int i = 0; i < 4; ++i) {
            const int xo = xob + i * 32;
            const int kk = xo >> 1;
            int sx0, sx1; float wx0, wx1;
            if ((xo & 1) == 0) { sx0 = kk > 0 ? kk - 1 : 0; sx1 = kk; wx0 = 0.25f; wx1 = 0.75f; }
            else               { sx0 = kk; sx1 = kk < 63 ? kk + 1 : 63; wx0 = 0.75f; wx1 = 0.25f; }
            unsigned pk[4];
            #pragma unroll
            for (int h = 0; h < 2; ++h) {
                const fx4 a0 = *(const fx4*)&Lt[rA][sx0][oct * 8 + h * 4];
                const fx4 a1 = *(const fx4*)&Lt[rA][sx1][oct * 8 + h * 4];
                const fx4 b0 = *(const fx4*)&Lt[rB][sx0][oct * 8 + h * 4];
                const fx4 b1 = *(const fx4*)&Lt[rB][sx1][oct * 8 + h * 4];
                #pragma unroll
                for (int j2 = 0; j2 < 2; ++j2) {
                    float v0 = wyA * (wx0 * a0[j2 * 2]     + wx1 * a1[j2 * 2])
                             + wyB * (wx0 * b0[j2 * 2]     + wx1 * b1[j2 * 2]);
                    float v1 = wyA * (wx0 * a0[j2 * 2 + 1] + wx1 * a1[j2 * 2 + 1])
                             + wyB * (wx0 * b0[j2 * 2 + 1] + wx1 * b1[j2 * 2 + 1]);
                    v0 *= sty[h * 4 + j2 * 2];
                    v1 *= sty[h * 4 + j2 * 2 + 1];
                    pk[h * 2 + j2] = (unsigned)f2bf(v0) | ((unsigned)f2bf(v1) << 16);
                }
            }
            *(int4*)&xu[((size_t)(b * 128 + yo) * 128 + xo) * 512 + c0 + oct * 8] =
                make_int4(pk[0], pk[1], pk[2], pk[3]);
        }
    }
}

// ---------------- 3x3 conv, implicit im2col, bf16 MFMA 16x16x32 ----------------
// (r2 structure — best measured: conv1 136.0us; per-phase barriers are load-
// bearing for L2 weight-stream reuse, see r6 post-mortem.) Tile: 128 Cout x
// 256 px, 8 waves of 64x64. A double-buffered at (ic,dy)-chunk granularity;
// B single-buffered, restaged once per ic. LDS = 80 KiB -> 2 blocks/CU.
// IS_CONV2: to_rgb fused into epilogue — per-pixel rgb partial dots reduced
// across lhi lanes (shfl_xor 16/32) and atomicAdd'ed into rgbpart (4 adds per
// address grid-wide); hs3 write + rgb kernel eliminated.
template<int CIN, bool IS_CONV2>
__global__ __launch_bounds__(512, 4) void conv3x3_kernel(
    const unsigned short* __restrict__ inp,
    const unsigned short* __restrict__ wpack,
    const float* __restrict__ dvec,
    const float* __restrict__ bias,
    const float* __restrict__ post,
    unsigned short* __restrict__ outmod,
    float* __restrict__ outf,
    const float* __restrict__ w3,
    float* __restrict__ rgbpart)
{
    constexpr int NIC = CIN / 32;
    __shared__ __attribute__((aligned(16))) short Alds[2][12288];   // 49152 B [buf][dx][kh][m128][e8]
    __shared__ __attribute__((aligned(16))) short Blds[4][128][32]; // 32768 B [row][px][ci-swz]
    const int tid = threadIdx.x;
    const int lane = tid & 63;
    const int wvi = tid >> 6;         // 0..7
    const int bid = blockIdx.x;       // grid 512 = b(4) x mblk(2) x y2(64)
    const int y0 = (bid & 63) << 1;
    const int mblk = (bid >> 6) & 1;
    const int b = bid >> 7;
    const int wm = (wvi >> 2) * 64;
    const int row = (wvi >> 1) & 1;   // which of the 2 output rows
    const int wn = (wvi & 1) * 64;
    const int lhi = lane >> 4;
    const int llo = lane & 15;

    const int xg = tid >> 2, i8 = tid & 3;
    const int i8s = i8 ^ ((xg >> 1) & 3);

    fx4 acc[4][4];
    #pragma unroll
    for (int mt = 0; mt < 4; ++mt)
        #pragma unroll
        for (int nt = 0; nt < 4; ++nt) acc[mt][nt] = (fx4){0.f, 0.f, 0.f, 0.f};

    // stage 4 input rows (y0-1 .. y0+2) of channel-chunk ic into Blds
    auto stageB = [&](int ic) {
        #pragma unroll
        for (int rr = 0; rr < 4; ++rr) {
            const int yy = y0 - 1 + rr;
            char* dstB = (char*)&Blds[rr][0][0] + tid * 16;
            if ((unsigned)yy < 128u) {
                gl_lds16(inp + ((size_t)(b * 128 + yy) * 128 + xg) * CIN + ic * 32 + i8s * 8, dstB);
            } else {
                *(int4*)dstB = make_int4(0, 0, 0, 0);
            }
        }
    };
    // stage one 24.6KB A chunk (ic,dy) into Alds[buf]
    auto stageA = [&](int ic, int dy, int buf) {
        const unsigned short* asrc = wpack + ((size_t)(mblk * 3 + dy) * NIC + ic) * 12288;
        #pragma unroll
        for (int j = 0; j < 3; ++j) {
            int g = tid + j * 512;
            gl_lds16(asrc + (size_t)g * 8, (char*)&Alds[buf][0] + g * 16);
        }
    };

    stageB(0);
    stageA(0, 0, 0);
    __syncthreads();

    int par = 0;
    for (int ic = 0; ic < NIC; ++ic) {
        #pragma unroll
        for (int dy = 0; dy < 3; ++dy) {
            const bool last = (ic == NIC - 1) && (dy == 2);
            if (!last) {
                const int nic = (dy == 2) ? ic + 1 : ic;
                const int ndy = (dy == 2) ? 0 : dy + 1;
                stageA(nic, ndy, par ^ 1);        // issue only; lands during MFMAs below
            }
            const short* Ab = &Alds[par][0];
            const short* Brow = &Blds[row + dy][0][0];
            #pragma unroll
            for (int dx = 0; dx < 3; ++dx) {
                bhalf8 af[4], bfr[4];
                #pragma unroll
                for (int mt = 0; mt < 4; ++mt)
                    af[mt] = *(const bhalf8*)&Ab[dx * 4096 + (lhi * 128 + wm + mt * 16 + llo) * 8];
                #pragma unroll
                for (int nt = 0; nt < 4; ++nt) {
                    const int s = wn + nt * 16 + llo + dx;
                    if ((nt == 0 && dx == 0) || (nt == 3 && dx == 2)) {
                        // s==0 (left of image) or s==129 (right of image): zero pad
                        const bool edge = (s == 0) || (s == 129);
                        const int sp = edge ? 0 : (s - 1);
                        const int key = (sp >> 1) & 3;
                        bhalf8 v = *(const bhalf8*)&Brow[sp * 32 + ((lhi ^ key) << 3)];
                        bhalf8 z = {0, 0, 0, 0, 0, 0, 0, 0};
                        bfr[nt] = edge ? z : v;
                    } else {
                        const int sp = s - 1;
                        const int key = (sp >> 1) & 3;
                        bfr[nt] = *(const bhalf8*)&Brow[sp * 32 + ((lhi ^ key) << 3)];
                    }
                }
                __builtin_amdgcn_s_setprio(1);
                #pragma unroll
                for (int mt = 0; mt < 4; ++mt)
                    #pragma unroll
                    for (int nt = 0; nt < 4; ++nt)
                        acc[mt][nt] = __builtin_amdgcn_mfma_f32_16x16x32_bf16(
                            af[mt], bfr[nt], acc[mt][nt], 0, 0, 0);
                __builtin_amdgcn_s_setprio(0);
            }
            if (dy == 2 && ic + 1 < NIC) {
                __syncthreads();      // all waves done reading B of this ic
                stageB(ic + 1);       // issue restage
            }
            if (!last) __syncthreads();   // A-prefetch (and B restage) landed & visible
            par ^= 1;
        }
    }

    // epilogue
    const int y = y0 + row;
    if constexpr (!IS_CONV2) {
        // conv1: write modulated bf16 (t1) only
        #pragma unroll
        for (int mt = 0; mt < 4; ++mt) {
            const int o0 = mblk * 128 + wm + mt * 16 + lhi * 4;
            const fx4 d4 = *(const fx4*)(dvec + b * 256 + o0);
            const fx4 bb4 = *(const fx4*)(bias + o0);
            const fx4 p4 = *(const fx4*)(post + b * 256 + o0);
            #pragma unroll
            for (int nt = 0; nt < 4; ++nt) {
                const int xo = wn + nt * 16 + llo;
                unsigned lo = 0, hi = 0;
                #pragma unroll
                for (int r = 0; r < 4; ++r) {
                    float v = acc[mt][nt][r] * d4[r] + bb4[r];
                    v = lrelu(v);
                    unsigned short ub = f2bf(v * p4[r]);
                    if (r < 2) lo |= (unsigned)ub << (16 * r);
                    else       hi |= (unsigned)ub << (16 * (r - 2));
                }
                *(uint2*)&outmod[((size_t)(b * 128 + y) * 128 + xo) * 256 + o0] = make_uint2(lo, hi);
            }
        }
    } else {
        // conv2: write h (f32) + fused to_rgb partial dots (no hs3 materialization)
        #pragma unroll
        for (int nt = 0; nt < 4; ++nt) {
            const int xo = wn + nt * 16 + llo;
            float pq0 = 0.f, pq1 = 0.f, pq2 = 0.f;
            #pragma unroll
            for (int mt = 0; mt < 4; ++mt) {
                const int o0 = mblk * 128 + wm + mt * 16 + lhi * 4;
                const fx4 d4 = *(const fx4*)(dvec + b * 256 + o0);
                const fx4 bb4 = *(const fx4*)(bias + o0);
                const fx4 p4 = *(const fx4*)(post + b * 256 + o0);
                const fx4 wq0 = *(const fx4*)(w3 + o0);
                const fx4 wq1 = *(const fx4*)(w3 + 256 + o0);
                const fx4 wq2 = *(const fx4*)(w3 + 512 + o0);
                #pragma unroll
                for (int r = 0; r < 4; ++r) {
                    float v = acc[mt][nt][r] * d4[r] + bb4[r];
                    v = lrelu(v);
                    outf[(((size_t)b * 256 + o0 + r) * 128 + y) * 128 + xo] = v;
                    const float hv = v * p4[r];
                    pq0 += wq0[r] * hv;
                    pq1 += wq1[r] * hv;
                    pq2 += wq2[r] * hv;
                }
            }
            pq0 += __shfl_xor(pq0, 16, 64); pq0 += __shfl_xor(pq0, 32, 64);
            pq1 += __shfl_xor(pq1, 16, 64); pq1 += __shfl_xor(pq1, 32, 64);
            pq2 += __shfl_xor(pq2, 16, 64); pq2 += __shfl_xor(pq2, 32, 64);
            if (lhi == 0) {
                float* rp = rgbpart + (size_t)b * 49152 + (size_t)y * 128 + xo;
                atomicAdd(rp, pq0);
                atomicAdd(rp + 16384, pq1);
                atomicAdd(rp + 32768, pq2);
            }
        }
    }
}

// ---------------- rgb finish: out = lrelu(partial + b3) ----------------
__global__ __launch_bounds__(256) void rgb_finish_kernel(
    const float* __restrict__ part, const float* __restrict__ b3,
    float* __restrict__ out)   // [4][3][128][128]
{
    int i = blockIdx.x * 256 + threadIdx.x;   // grid 768 -> 196608
    int q = (i >> 14) % 3;
    out[i] = lrelu(part[i] + b3[q]);
}

extern "C" void kernel_launch(void* const* d_in, const int* in_sizes, int n_in,
                              void* d_out, int out_size, void* d_ws, size_t ws_size,
                              hipStream_t stream) {
    const float* x   = (const float*)d_in[0];
    const float* w   = (const float*)d_in[1];
    const float* w1  = (const float*)d_in[2];
    const float* b1  = (const float*)d_in[3];
    const float* a1w = (const float*)d_in[4];
    const float* a1b = (const float*)d_in[5];
    const float* w2  = (const float*)d_in[6];
    const float* b2  = (const float*)d_in[7];
    const float* a2w = (const float*)d_in[8];
    const float* a2b = (const float*)d_in[9];
    const float* w3  = (const float*)d_in[10];
    const float* b3  = (const float*)d_in[11];
    const float* a3w = (const float*)d_in[12];
    const float* a3b = (const float*)d_in[13];

    char* ws = (char*)d_ws;
    unsigned short* xu  = (unsigned short*)(ws);                 // 67108864 B [4][128][128][512] bf16
    unsigned short* t1  = (unsigned short*)(ws + 67108864);      // 33554432 B [4][128][128][256] bf16
    unsigned short* wp1 = (unsigned short*)(ws + 100663296);     // 2359296 B
    unsigned short* wp2 = (unsigned short*)(ws + 103022592);     // 1179648 B
    float* s1 = (float*)(ws + 104202240);                        // 4*512
    float* s2 = (float*)(ws + 104210432);                        // 4*256
    float* s3 = (float*)(ws + 104214528);                        // 4*256
    float* d1 = (float*)(ws + 104218624);                        // 4*256
    float* d2 = (float*)(ws + 104222720);                        // 4*256
    float* rgbpart = (float*)(ws + 104226816);                   // 786432 B [4][3][128][128] f32

    float* h_out   = (float*)d_out;
    float* rgb_out = h_out + 16777216;

    hipMemsetAsync(rgbpart, 0, 786432, stream);
    style_kernel<<<1024, 256, 0, stream>>>(w, a1w, a1b, a2w, a2b, a3w, a3b, s1, s2, s3);
    demod_kernel<<<2048, 256, 0, stream>>>(w1, w2, s1, s2, d1, d2);
    pack_kernel<<<6912, 256, 0, stream>>>(w1, w2, wp1, wp2);
    upsample_kernel<<<2048, 256, 0, stream>>>(x, s1, xu);
    conv3x3_kernel<512, false><<<512, 512, 0, stream>>>(xu, wp1, d1, b1, s2, t1, nullptr, nullptr, nullptr);
    conv3x3_kernel<256, true><<<512, 512, 0, stream>>>(t1, wp2, d2, b2, s3, nullptr, h_out, w3, rgbpart);
    rgb_finish_kernel<<<768, 256, 0, stream>>>(rgbpart, b3, rgb_out);
}

// Round 8
// 353.548 us; speedup vs baseline: 2.2409x; 1.0033x over previous
//
#include <hip/hip_runtime.h>
#include <stdint.h>

typedef __attribute__((ext_vector_type(8))) short bhalf8;
typedef __attribute__((ext_vector_type(4))) float fx4;

__device__ __forceinline__ unsigned short f2bf(float f) {
    unsigned u = __builtin_bit_cast(unsigned, f);
    unsigned r = (u + 0x7fffu + ((u >> 16) & 1u)) >> 16;
    return (unsigned short)r;
}
__device__ __forceinline__ float bf2f(unsigned short h) {
    unsigned u = ((unsigned)h) << 16;
    return __builtin_bit_cast(float, u);
}
__device__ __forceinline__ float lrelu(float v) { return v > 0.f ? v : 0.2f * v; }

typedef __attribute__((address_space(1))) void as1_void;
typedef __attribute__((address_space(3))) void as3_void;
__device__ __forceinline__ void gl_lds16(const void* g, void* l) {
    __builtin_amdgcn_global_load_lds((as1_void*)(void*)g, (as3_void*)l, 16, 0, 0);
}

// ---------------- prep: pack (0-6911) | style (6912-7935) | rgbpart zero (7936-8703) ----------------
__global__ __launch_bounds__(256) void prep_kernel(
    const float* __restrict__ w1, const float* __restrict__ w2,
    unsigned short* __restrict__ wp1, unsigned short* __restrict__ wp2,
    const float* __restrict__ w,
    const float* __restrict__ a1w, const float* __restrict__ a1b,
    const float* __restrict__ a2w, const float* __restrict__ a2b,
    const float* __restrict__ a3w, const float* __restrict__ a3b,
    float* __restrict__ s1, float* __restrict__ s2, float* __restrict__ s3,
    float* __restrict__ rgbpart)
{
    const int bid = blockIdx.x;
    const int t = threadIdx.x;
    if (bid < 6912) {
        // ---- pack weights to bf16, fragment-linear [mblk][dy][ic][dx][kh][m128][e8] ----
        int tid = bid * 256 + t;
        const int N1 = 1179648, N2 = 589824;
        if (tid < N1) {
            int e = tid & 7, m = (tid >> 3) & 127, kh = (tid >> 10) & 3;
            int dx = (tid >> 12) % 3, ic = (tid / 12288) & 15;
            int dy = (tid / 196608) % 3, mblk = tid / 589824;
            int o = mblk * 128 + m, ci = ic * 32 + kh * 8 + e;
            wp1[tid] = f2bf(w1[((size_t)o * 512 + ci) * 9 + dy * 3 + dx]);
        } else if (tid < N1 + N2) {
            int t2 = tid - N1;
            int e = t2 & 7, m = (t2 >> 3) & 127, kh = (t2 >> 10) & 3;
            int dx = (t2 >> 12) % 3, ic = (t2 / 12288) & 7;
            int dy = (t2 / 98304) % 3, mblk = t2 / 294912;
            int o = mblk * 128 + m, ci = ic * 32 + kh * 8 + e;
            wp2[t2] = f2bf(w2[((size_t)o * 256 + ci) * 9 + dy * 3 + dx]);
        }
    } else if (bid < 7936) {
        // ---- styles: s = w @ a^T + b (one wave per output) ----
        int gw = (bid - 6912) * 4 + (t >> 6);   // 0..4095
        int lane = t & 63;
        int b = gw >> 10, r = gw & 1023;
        const float* arow; const float* abias; float* dst;
        if (r < 512)      { arow = a1w + (size_t)r * 512;        abias = a1b + r;       dst = s1 + b * 512 + r; }
        else if (r < 768) { int rr = r - 512; arow = a2w + (size_t)rr * 512; abias = a2b + rr; dst = s2 + b * 256 + rr; }
        else              { int rr = r - 768; arow = a3w + (size_t)rr * 512; abias = a3b + rr; dst = s3 + b * 256 + rr; }
        const float* wrow = w + b * 512;
        float acc = 0.f;
        #pragma unroll
        for (int j = 0; j < 8; ++j) {
            int c = lane + j * 64;
            acc += wrow[c] * arow[c];
        }
        #pragma unroll
        for (int off = 32; off; off >>= 1) acc += __shfl_down(acc, off, 64);
        if (lane == 0) *dst = acc + *abias;
    } else {
        // ---- zero rgb partial buffer (replaces hipMemsetAsync dispatch) ----
        int i = (bid - 7936) * 256 + t;   // 768 blocks -> 196608 floats
        rgbpart[i] = 0.f;
    }
}

// ---------------- upsample (0-2047) | demod (2048-4095) ----------------
__global__ __launch_bounds__(256) void us_demod_kernel(
    const float* __restrict__ x, const float* __restrict__ s1,
    unsigned short* __restrict__ xu,   // [4][128][128][512]
    const float* __restrict__ w1, const float* __restrict__ w2,
    const float* __restrict__ s2,
    float* __restrict__ d1, float* __restrict__ d2)
{
    const int bidg = blockIdx.x;
    const int t = threadIdx.x;
    if (bidg < 2048) {
        // ---- bilinear 2x upsample + s1 modulate -> bf16 channels-last ----
        __shared__ float Lt[3][64][68];   // 52224 B
        const int bid = bidg;             // b(4) x k(64) x cchunk(8)
        const int cch = bid & 7, k = (bid >> 3) & 63, b = bid >> 9;
        const int c0 = cch * 64;
        {
            const int px4 = t & 15, cc4 = t >> 4;   // cc4 0..15
            #pragma unroll
            for (int r = 0; r < 3; ++r) {
                int sy = k - 1 + r; sy = sy < 0 ? 0 : (sy > 63 ? 63 : sy);
                float4 v[4];
                #pragma unroll
                for (int j = 0; j < 4; ++j)
                    v[j] = *(const float4*)&x[((size_t)(b * 512 + c0 + cc4 * 4 + j) * 64 + sy) * 64 + px4 * 4];
                #pragma unroll
                for (int o = 0; o < 4; ++o) {
                    fx4 w4;
                    w4[0] = ((const float*)&v[0])[o];
                    w4[1] = ((const float*)&v[1])[o];
                    w4[2] = ((const float*)&v[2])[o];
                    w4[3] = ((const float*)&v[3])[o];
                    *(fx4*)&Lt[r][px4 * 4 + o][cc4 * 4] = w4;
                }
            }
        }
        __syncthreads();

        const int oct = t & 7, xob = t >> 3;   // xob 0..31
        float sty[8];
        #pragma unroll
        for (int j = 0; j < 8; ++j) sty[j] = s1[b * 512 + c0 + oct * 8 + j];

        #pragma unroll
        for (int half = 0; half < 2; ++half) {     // out row 2k+half
            const int yo = 2 * k + half;
            const int rA = half ? 1 : 0, rB = rA + 1;
            const float wyA = half ? 0.75f : 0.25f, wyB = half ? 0.25f : 0.75f;
            #pragma unroll
            for (int i = 0; i < 4; ++i) {
                const int xo = xob + i * 32;
                const int kk = xo >> 1;
                int sx0, sx1; float wx0, wx1;
                if ((xo & 1) == 0) { sx0 = kk > 0 ? kk - 1 : 0; sx1 = kk; wx0 = 0.25f; wx1 = 0.75f; }
                else               { sx0 = kk; sx1 = kk < 63 ? kk + 1 : 63; wx0 = 0.75f; wx1 = 0.25f; }
                unsigned pk[4];
                #pragma unroll
                for (int h = 0; h < 2; ++h) {
                    const fx4 a0 = *(const fx4*)&Lt[rA][sx0][oct * 8 + h * 4];
                    const fx4 a1 = *(const fx4*)&Lt[rA][sx1][oct * 8 + h * 4];
                    const fx4 b0 = *(const fx4*)&Lt[rB][sx0][oct * 8 + h * 4];
                    const fx4 b1 = *(const fx4*)&Lt[rB][sx1][oct * 8 + h * 4];
                    #pragma unroll
                    for (int j2 = 0; j2 < 2; ++j2) {
                        float v0 = wyA * (wx0 * a0[j2 * 2]     + wx1 * a1[j2 * 2])
                                 + wyB * (wx0 * b0[j2 * 2]     + wx1 * b1[j2 * 2]);
                        float v1 = wyA * (wx0 * a0[j2 * 2 + 1] + wx1 * a1[j2 * 2 + 1])
                                 + wyB * (wx0 * b0[j2 * 2 + 1] + wx1 * b1[j2 * 2 + 1]);
                        v0 *= sty[h * 4 + j2 * 2];
                        v1 *= sty[h * 4 + j2 * 2 + 1];
                        pk[h * 2 + j2] = (unsigned)f2bf(v0) | ((unsigned)f2bf(v1) << 16);
                    }
                }
                *(int4*)&xu[((size_t)(b * 128 + yo) * 128 + xo) * 512 + c0 + oct * 8] =
                    make_int4(pk[0], pk[1], pk[2], pk[3]);
            }
        }
    } else {
        // ---- demod: d[b,o] = rsqrt(sum_{i,tap}(w*s)^2 + eps) ----
        __shared__ float sv[512];
        __shared__ float red[4];
        int blk = bidg - 2048;            // 2048 blocks
        int conv = blk >> 10, b = (blk >> 8) & 3, o = blk & 255;
        int cin = conv ? 256 : 512;
        const float* s = conv ? (s2 + b * 256) : (s1 + b * 512);
        const float* row = (conv ? w2 : w1) + (size_t)o * cin * 9;
        for (int i = t; i < cin; i += 256) { float v = s[i]; sv[i] = v * v; }
        __syncthreads();
        float sum = 0.f;
        int n = cin * 9;
        for (int k = t; k < n; k += 256) {
            float v = row[k];
            sum += v * v * sv[k / 9];
        }
        #pragma unroll
        for (int off = 32; off; off >>= 1) sum += __shfl_down(sum, off, 64);
        if ((t & 63) == 0) red[t >> 6] = sum;
        __syncthreads();
        if (t == 0) {
            float tot = red[0] + red[1] + red[2] + red[3];
            (conv ? d2 : d1)[b * 256 + o] = rsqrtf(tot + 1e-8f);
        }
    }
}

// ---------------- 3x3 conv, implicit im2col, bf16 MFMA 16x16x32 ----------------
// (r2 structure — best measured: conv1 136.0us; per-phase barriers are load-
// bearing for L2 weight-stream reuse, see r6 post-mortem.) Tile: 128 Cout x
// 256 px, 8 waves of 64x64. A double-buffered at (ic,dy)-chunk granularity;
// B single-buffered, restaged once per ic. LDS = 80 KiB -> 2 blocks/CU.
// IS_CONV2: to_rgb fused into epilogue — per-pixel rgb partial dots reduced
// across lhi lanes (shfl_xor 16/32) and atomicAdd'ed into rgbpart (4 adds per
// address grid-wide); hs3 write + rgb kernel eliminated.
template<int CIN, bool IS_CONV2>
__global__ __launch_bounds__(512, 4) void conv3x3_kernel(
    const unsigned short* __restrict__ inp,
    const unsigned short* __restrict__ wpack,
    const float* __restrict__ dvec,
    const float* __restrict__ bias,
    const float* __restrict__ post,
    unsigned short* __restrict__ outmod,
    float* __restrict__ outf,
    const float* __restrict__ w3,
    float* __restrict__ rgbpart)
{
    constexpr int NIC = CIN / 32;
    __shared__ __attribute__((aligned(16))) short Alds[2][12288];   // 49152 B [buf][dx][kh][m128][e8]
    __shared__ __attribute__((aligned(16))) short Blds[4][128][32]; // 32768 B [row][px][ci-swz]
    const int tid = threadIdx.x;
    const int lane = tid & 63;
    const int wvi = tid >> 6;         // 0..7
    const int bid = blockIdx.x;       // grid 512 = b(4) x mblk(2) x y2(64)
    const int y0 = (bid & 63) << 1;
    const int mblk = (bid >> 6) & 1;
    const int b = bid >> 7;
    const int wm = (wvi >> 2) * 64;
    const int row = (wvi >> 1) & 1;   // which of the 2 output rows
    const int wn = (wvi & 1) * 64;
    const int lhi = lane >> 4;
    const int llo = lane & 15;

    const int xg = tid >> 2, i8 = tid & 3;
    const int i8s = i8 ^ ((xg >> 1) & 3);

    fx4 acc[4][4];
    #pragma unroll
    for (int mt = 0; mt < 4; ++mt)
        #pragma unroll
        for (int nt = 0; nt < 4; ++nt) acc[mt][nt] = (fx4){0.f, 0.f, 0.f, 0.f};

    // stage 4 input rows (y0-1 .. y0+2) of channel-chunk ic into Blds
    auto stageB = [&](int ic) {
        #pragma unroll
        for (int rr = 0; rr < 4; ++rr) {
            const int yy = y0 - 1 + rr;
            char* dstB = (char*)&Blds[rr][0][0] + tid * 16;
            if ((unsigned)yy < 128u) {
                gl_lds16(inp + ((size_t)(b * 128 + yy) * 128 + xg) * CIN + ic * 32 + i8s * 8, dstB);
            } else {
                *(int4*)dstB = make_int4(0, 0, 0, 0);
            }
        }
    };
    // stage one 24.6KB A chunk (ic,dy) into Alds[buf]
    auto stageA = [&](int ic, int dy, int buf) {
        const unsigned short* asrc = wpack + ((size_t)(mblk * 3 + dy) * NIC + ic) * 12288;
        #pragma unroll
        for (int j = 0; j < 3; ++j) {
            int g = tid + j * 512;
            gl_lds16(asrc + (size_t)g * 8, (char*)&Alds[buf][0] + g * 16);
        }
    };

    stageB(0);
    stageA(0, 0, 0);
    __syncthreads();

    int par = 0;
    for (int ic = 0; ic < NIC; ++ic) {
        #pragma unroll
        for (int dy = 0; dy < 3; ++dy) {
            const bool last = (ic == NIC - 1) && (dy == 2);
            if (!last) {
                const int nic = (dy == 2) ? ic + 1 : ic;
                const int ndy = (dy == 2) ? 0 : dy + 1;
                stageA(nic, ndy, par ^ 1);        // issue only; lands during MFMAs below
            }
            const short* Ab = &Alds[par][0];
            const short* Brow = &Blds[row + dy][0][0];
            #pragma unroll
            for (int dx = 0; dx < 3; ++dx) {
                bhalf8 af[4], bfr[4];
                #pragma unroll
                for (int mt = 0; mt < 4; ++mt)
                    af[mt] = *(const bhalf8*)&Ab[dx * 4096 + (lhi * 128 + wm + mt * 16 + llo) * 8];
                #pragma unroll
                for (int nt = 0; nt < 4; ++nt) {
                    const int s = wn + nt * 16 + llo + dx;
                    if ((nt == 0 && dx == 0) || (nt == 3 && dx == 2)) {
                        // s==0 (left of image) or s==129 (right of image): zero pad
                        const bool edge = (s == 0) || (s == 129);
                        const int sp = edge ? 0 : (s - 1);
                        const int key = (sp >> 1) & 3;
                        bhalf8 v = *(const bhalf8*)&Brow[sp * 32 + ((lhi ^ key) << 3)];
                        bhalf8 z = {0, 0, 0, 0, 0, 0, 0, 0};
                        bfr[nt] = edge ? z : v;
                    } else {
                        const int sp = s - 1;
                        const int key = (sp >> 1) & 3;
                        bfr[nt] = *(const bhalf8*)&Brow[sp * 32 + ((lhi ^ key) << 3)];
                    }
                }
                __builtin_amdgcn_s_setprio(1);
                #pragma unroll
                for (int mt = 0; mt < 4; ++mt)
                    #pragma unroll
                    for (int nt = 0; nt < 4; ++nt)
                        acc[mt][nt] = __builtin_amdgcn_mfma_f32_16x16x32_bf16(
                            af[mt], bfr[nt], acc[mt][nt], 0, 0, 0);
                __builtin_amdgcn_s_setprio(0);
            }
            if (dy == 2 && ic + 1 < NIC) {
                __syncthreads();      // all waves done reading B of this ic
                stageB(ic + 1);       // issue restage
            }
            if (!last) __syncthreads();   // A-prefetch (and B restage) landed & visible
            par ^= 1;
        }
    }

    // epilogue
    const int y = y0 + row;
    if constexpr (!IS_CONV2) {
        // conv1: write modulated bf16 (t1) only
        #pragma unroll
        for (int mt = 0; mt < 4; ++mt) {
            const int o0 = mblk * 128 + wm + mt * 16 + lhi * 4;
            const fx4 d4 = *(const fx4*)(dvec + b * 256 + o0);
            const fx4 bb4 = *(const fx4*)(bias + o0);
            const fx4 p4 = *(const fx4*)(post + b * 256 + o0);
            #pragma unroll
            for (int nt = 0; nt < 4; ++nt) {
                const int xo = wn + nt * 16 + llo;
                unsigned lo = 0, hi = 0;
                #pragma unroll
                for (int r = 0; r < 4; ++r) {
                    float v = acc[mt][nt][r] * d4[r] + bb4[r];
                    v = lrelu(v);
                    unsigned short ub = f2bf(v * p4[r]);
                    if (r < 2) lo |= (unsigned)ub << (16 * r);
                    else       hi |= (unsigned)ub << (16 * (r - 2));
                }
                *(uint2*)&outmod[((size_t)(b * 128 + y) * 128 + xo) * 256 + o0] = make_uint2(lo, hi);
            }
        }
    } else {
        // conv2: write h (f32) + fused to_rgb partial dots (no hs3 materialization)
        #pragma unroll
        for (int nt = 0; nt < 4; ++nt) {
            const int xo = wn + nt * 16 + llo;
            float pq0 = 0.f, pq1 = 0.f, pq2 = 0.f;
            #pragma unroll
            for (int mt = 0; mt < 4; ++mt) {
                const int o0 = mblk * 128 + wm + mt * 16 + lhi * 4;
                const fx4 d4 = *(const fx4*)(dvec + b * 256 + o0);
                const fx4 bb4 = *(const fx4*)(bias + o0);
                const fx4 p4 = *(const fx4*)(post + b * 256 + o0);
                const fx4 wq0 = *(const fx4*)(w3 + o0);
                const fx4 wq1 = *(const fx4*)(w3 + 256 + o0);
                const fx4 wq2 = *(const fx4*)(w3 + 512 + o0);
                #pragma unroll
                for (int r = 0; r < 4; ++r) {
                    float v = acc[mt][nt][r] * d4[r] + bb4[r];
                    v = lrelu(v);
                    outf[(((size_t)b * 256 + o0 + r) * 128 + y) * 128 + xo] = v;
                    const float hv = v * p4[r];
                    pq0 += wq0[r] * hv;
                    pq1 += wq1[r] * hv;
                    pq2 += wq2[r] * hv;
                }
            }
            pq0 += __shfl_xor(pq0, 16, 64); pq0 += __shfl_xor(pq0, 32, 64);
            pq1 += __shfl_xor(pq1, 16, 64); pq1 += __shfl_xor(pq1, 32, 64);
            pq2 += __shfl_xor(pq2, 16, 64); pq2 += __shfl_xor(pq2, 32, 64);
            if (lhi == 0) {
                float* rp = rgbpart + (size_t)b * 49152 + (size_t)y * 128 + xo;
                atomicAdd(rp, pq0);
                atomicAdd(rp + 16384, pq1);
                atomicAdd(rp + 32768, pq2);
            }
        }
    }
}

// ---------------- rgb finish: out = lrelu(partial + b3) ----------------
__global__ __launch_bounds__(256) void rgb_finish_kernel(
    const float* __restrict__ part, const float* __restrict__ b3,
    float* __restrict__ out)   // [4][3][128][128]
{
    int i = blockIdx.x * 256 + threadIdx.x;   // grid 768 -> 196608
    int q = (i >> 14) % 3;
    out[i] = lrelu(part[i] + b3[q]);
}

extern "C" void kernel_launch(void* const* d_in, const int* in_sizes, int n_in,
                              void* d_out, int out_size, void* d_ws, size_t ws_size,
                              hipStream_t stream) {
    const float* x   = (const float*)d_in[0];
    const float* w   = (const float*)d_in[1];
    const float* w1  = (const float*)d_in[2];
    const float* b1  = (const float*)d_in[3];
    const float* a1w = (const float*)d_in[4];
    const float* a1b = (const float*)d_in[5];
    const float* w2  = (const float*)d_in[6];
    const float* b2  = (const float*)d_in[7];
    const float* a2w = (const float*)d_in[8];
    const float* a2b = (const float*)d_in[9];
    const float* w3  = (const float*)d_in[10];
    const float* b3  = (const float*)d_in[11];
    const float* a3w = (const float*)d_in[12];
    const float* a3b = (const float*)d_in[13];

    char* ws = (char*)d_ws;
    unsigned short* xu  = (unsigned short*)(ws);                 // 67108864 B [4][128][128][512] bf16
    unsigned short* t1  = (unsigned short*)(ws + 67108864);      // 33554432 B [4][128][128][256] bf16
    unsigned short* wp1 = (unsigned short*)(ws + 100663296);     // 2359296 B
    unsigned short* wp2 = (unsigned short*)(ws + 103022592);     // 1179648 B
    float* s1 = (float*)(ws + 104202240);                        // 4*512
    float* s2 = (float*)(ws + 104210432);                        // 4*256
    float* s3 = (float*)(ws + 104214528);                        // 4*256
    float* d1 = (float*)(ws + 104218624);                        // 4*256
    float* d2 = (float*)(ws + 104222720);                        // 4*256
    float* rgbpart = (float*)(ws + 104226816);                   // 786432 B [4][3][128][128] f32

    float* h_out   = (float*)d_out;
    float* rgb_out = h_out + 16777216;

    prep_kernel<<<8704, 256, 0, stream>>>(w1, w2, wp1, wp2,
                                          w, a1w, a1b, a2w, a2b, a3w, a3b,
                                          s1, s2, s3, rgbpart);
    us_demod_kernel<<<4096, 256, 0, stream>>>(x, s1, xu, w1, w2, s2, d1, d2);
    conv3x3_kernel<512, false><<<512, 512, 0, stream>>>(xu, wp1, d1, b1, s2, t1, nullptr, nullptr, nullptr);
    conv3x3_kernel<256, true><<<512, 512, 0, stream>>>(t1, wp2, d2, b2, s3, nullptr, h_out, w3, rgbpart);
    rgb_finish_kernel<<<768, 256, 0, stream>>>(rgbpart, b3, rgb_out);
}